// Round 14
// baseline (358.866 us; speedup 1.0000x reference)
//
#include <hip/hip_runtime.h>
#include <hip/hip_bf16.h>
#include <stdint.h>

// B=8, S=2048, D=512, H=2, hd=256. All dims hardcoded.
// 6 dispatches: f2b_w (weights only) -> proj GEMM (A = f32 direct) -> gate
//   -> QKV GEMM (merged, XCD-swizzled; Q/K/V stored FP8 e4m3, K pre-swizzled,
//   V XOR-swizzled) -> attn (FP8 MFMA, 2-wave blocks / 4 barrier domains per CU)
//   -> final GEMM (mix fused in A-staging, +residual, f32 out)

typedef __bf16 bf16_t;
typedef __bf16 bf16x8 __attribute__((ext_vector_type(8)));
typedef float f32x4 __attribute__((ext_vector_type(4)));
typedef float f32x16 __attribute__((ext_vector_type(16)));
typedef unsigned int u32;
typedef unsigned char u8;

typedef void gvoid_t __attribute__((address_space(1)));
typedef void svoid_t __attribute__((address_space(3)));

__device__ inline void gload16(const void* g, void* l) {
    __builtin_amdgcn_global_load_lds((gvoid_t*)g, (svoid_t*)l, 16, 0, 0);
}

__device__ inline float exp2v(float x) {
    float r;
    asm("v_exp_f32 %0, %1" : "=v"(r) : "v"(x));
    return r;
}

// hiword selector must be a compile-time literal for the builtin.
template <bool HI>
__device__ inline u32 pk_fp8(float a, float b, u32 old) {
    return (u32)__builtin_amdgcn_cvt_pk_fp8_f32(a, b, (int)old, HI);
}
__device__ inline u8 to_fp8(float a) { return (u8)(pk_fp8<false>(a, a, 0) & 0xff); }
__device__ inline long pk64(u32 lo, u32 hi) {
    return (long)(((unsigned long long)hi << 32) | (unsigned long long)lo);
}
__device__ inline f32x16 mfma_fp8(long a, long b, f32x16 c) {
    return __builtin_amdgcn_mfma_f32_32x32x16_fp8_fp8(a, b, c, 0, 0, 0);
}

// ---------------- weights f32 -> bf16 (w_rgb|w_event|w_in|w_out) ------------
__global__ __launch_bounds__(256) void f2b_w(const float* __restrict__ s2, bf16_t* __restrict__ d2,
                                             const float* __restrict__ s3, bf16_t* __restrict__ d3,
                                             const float* __restrict__ s4, bf16_t* __restrict__ d4,
                                             const float* __restrict__ s5, bf16_t* __restrict__ d5) {
    int i = blockIdx.x * 256 + threadIdx.x;
    const float* s; bf16_t* d; int off;
    if (i < 32768)       { s = s2; d = d2; off = i; }
    else if (i < 65536)  { s = s3; d = d3; off = i - 32768; }
    else if (i < 163840) { s = s4; d = d4; off = i - 65536; }
    else                 { s = s5; d = d5; off = i - 163840; }
    const float4* p = reinterpret_cast<const float4*>(s) + (size_t)off * 2;
    float4 a = p[0], b = p[1];
    bf16x8 o;
    o[0] = (bf16_t)a.x; o[1] = (bf16_t)a.y; o[2] = (bf16_t)a.z; o[3] = (bf16_t)a.w;
    o[4] = (bf16_t)b.x; o[5] = (bf16_t)b.y; o[6] = (bf16_t)b.z; o[7] = (bf16_t)b.w;
    reinterpret_cast<bf16x8*>(d)[off] = o;
}

// ---------------- GEMM: C = A @ B^T, 128x128 tile, BK=64, 4 waves ----------
// MODE 0 (proj): A = f32 inputs (reg-staged convert); y<128 rgb else event.
// MODE 1 (QKV, merged, XCD-swizzled grid 3072), all outputs FP8 e4m3:
//   Q -> qdst[row][512] bytes (natural scale)
//   K -> kdst[bh][kt][r*256 + hi_d*128 + (d>>4)*8 + (d&7)] ^ ((r&7)<<4)
//   V -> vdst[bh][kt][(d*32 + hi_k*16 + s*8 + j) ^ ((d&7)<<4)]  (k = s*16+hi_k*8+j)
// MODE 2 (final): A-staging = gate-mix of A,A2; f32 out + residual
template <int MODE>
__global__ __launch_bounds__(256) void gemm_bt(const float* __restrict__ Af,
                                               const float* __restrict__ Af2,
                                               const bf16_t* __restrict__ A,
                                               const bf16_t* __restrict__ A2,
                                               const bf16_t* __restrict__ Bw,
                                               const bf16_t* __restrict__ Bw2,
                                               const float* __restrict__ bias,
                                               const float* __restrict__ bias2,
                                               void* __restrict__ Cout,
                                               void* __restrict__ Cout2,
                                               const bf16_t* __restrict__ r1,
                                               const bf16_t* __restrict__ r2,
                                               const float* __restrict__ gate,
                                               u8* __restrict__ qdst,
                                               u8* __restrict__ kdst,
                                               u8* __restrict__ vdst,
                                               u8* __restrict__ qdst2,
                                               u8* __restrict__ kdst2,
                                               u8* __restrict__ vdst2,
                                               int N, int K) {
    __shared__ __align__(16) bf16_t As[128][64];
    __shared__ __align__(16) bf16_t Bs[128][64];
    const int tid = threadIdx.x, lane = tid & 63, w = tid >> 6;
    const int l16 = lane & 15, l4 = lane >> 4;
    const int wm = w >> 1, wn = w & 1;
    int xt, yt;
    if (MODE == 1) {
        int bid = blockIdx.x;          // 3072 = 12x * 256y, XCD-grouped
        int xcd = bid & 7, idx = bid >> 3;   // idx 0..383
        yt = xcd + 8 * (idx / 12);           // x-fastest within XCD
        xt = idx % 12;
    } else {
        xt = blockIdx.x; yt = blockIdx.y;
    }
    const bool sec = (MODE != 2) && (yt >= 128);
    const size_t a0 = (size_t)(yt & 127) * 128;
    const size_t b0 = (size_t)xt * 128;
    const bf16_t* Ap = sec ? A2 : A;
    const bf16_t* Bp = sec ? Bw2 : Bw;
    const float* Afp = sec ? Af2 : Af;
    const float* bp = sec ? bias2 : bias;
    f32x4 acc[4][4] = {};
    const int srow = w * 32 + (lane >> 3);
    const int scol = (lane & 7) * 8;
    float g4[4];
    if (MODE == 2) {
#pragma unroll
        for (int i = 0; i < 4; ++i) g4[i] = gate[a0 + srow + i * 8];
    }
    for (int kt = 0; kt < K; kt += 64) {
        __syncthreads();
        if (MODE == 0) {
#pragma unroll
            for (int i = 0; i < 4; ++i) {
                const float4* p = reinterpret_cast<const float4*>(
                    Afp + (a0 + srow + i * 8) * (size_t)K + kt + scol);
                float4 x = p[0], y = p[1];
                bf16x8 o;
                o[0] = (bf16_t)x.x; o[1] = (bf16_t)x.y; o[2] = (bf16_t)x.z; o[3] = (bf16_t)x.w;
                o[4] = (bf16_t)y.x; o[5] = (bf16_t)y.y; o[6] = (bf16_t)y.z; o[7] = (bf16_t)y.w;
                *reinterpret_cast<bf16x8*>(&As[srow + i * 8][scol]) = o;
            }
        } else if (MODE == 2) {
#pragma unroll
            for (int i = 0; i < 4; ++i) {
                size_t ro = (a0 + srow + i * 8) * (size_t)K + kt + scol;
                bf16x8 x = *reinterpret_cast<const bf16x8*>(A + ro);
                bf16x8 y = *reinterpret_cast<const bf16x8*>(A2 + ro);
                bf16x8 o;
#pragma unroll
                for (int j = 0; j < 8; ++j)
                    o[j] = (bf16_t)(g4[i] * (float)x[j] + (1.f - g4[i]) * (float)y[j]);
                *reinterpret_cast<bf16x8*>(&As[srow + i * 8][scol]) = o;
            }
        } else {
#pragma unroll
            for (int i = 0; i < 4; ++i)
                gload16(Ap + (a0 + srow + i * 8) * (size_t)K + kt + scol, &As[w * 32 + i * 8][0]);
        }
#pragma unroll
        for (int i = 0; i < 4; ++i)
            gload16(Bp + (b0 + srow + i * 8) * (size_t)K + kt + scol, &Bs[w * 32 + i * 8][0]);
        __syncthreads();
#pragma unroll
        for (int kk = 0; kk < 2; ++kk) {
            bf16x8 af[4], bfr[4];
#pragma unroll
            for (int mi = 0; mi < 4; ++mi)
                af[mi] = *reinterpret_cast<const bf16x8*>(&As[wm * 64 + mi * 16 + l16][kk * 32 + l4 * 8]);
#pragma unroll
            for (int ni = 0; ni < 4; ++ni)
                bfr[ni] = *reinterpret_cast<const bf16x8*>(&Bs[wn * 64 + ni * 16 + l16][kk * 32 + l4 * 8]);
#pragma unroll
            for (int mi = 0; mi < 4; ++mi)
#pragma unroll
                for (int ni = 0; ni < 4; ++ni)
                    acc[mi][ni] = __builtin_amdgcn_mfma_f32_16x16x32_bf16(af[mi], bfr[ni], acc[mi][ni], 0, 0, 0);
        }
    }
    u8* qd = sec ? qdst2 : qdst;
    u8* kd = sec ? kdst2 : kdst;
    u8* vd = sec ? vdst2 : vdst;
#pragma unroll
    for (int mi = 0; mi < 4; ++mi) {
#pragma unroll
        for (int ni = 0; ni < 4; ++ni) {
            int col = (int)b0 + wn * 64 + ni * 16 + l16;
            float bs = bp[col];
            int row0 = (int)a0 + wm * 64 + mi * 16 + l4 * 4;
            float vv[4];
#pragma unroll
            for (int r = 0; r < 4; ++r) vv[r] = acc[mi][ni][r] + bs;
            if (MODE == 0) {
                bf16_t* Cp = (bf16_t*)(sec ? Cout2 : Cout);
#pragma unroll
                for (int r = 0; r < 4; ++r)
                    Cp[(size_t)(row0 + r) * N + col] = (bf16_t)vv[r];
            } else if (MODE == 2) {
#pragma unroll
                for (int r = 0; r < 4; ++r) {
                    size_t idx = (size_t)(row0 + r) * N + col;
                    ((float*)Cout)[idx] = vv[r] + 0.5f * ((float)r1[idx] + (float)r2[idx]);
                }
            } else {
                if (col < 512) {
#pragma unroll
                    for (int r = 0; r < 4; ++r)
                        qd[(size_t)(row0 + r) * 512 + col] = to_fp8(vv[r]);
                } else if (col < 1024) {
                    int cc = col - 512, hh = cc >> 8, d = cc & 255;
                    int dpart = ((d >> 3) & 1) * 128 + (d >> 4) * 8 + (d & 7);
#pragma unroll
                    for (int r = 0; r < 4; ++r) {
                        int row = row0 + r;
                        int bh = (row >> 11) * 2 + hh, seq = row & 2047;
                        int rr = seq & 31;
                        u32 boff = (u32)(rr * 256 + dpart) ^ (u32)((rr & 7) << 4);
                        kd[((size_t)(bh * 64 + (seq >> 5))) * 8192 + boff] = to_fp8(vv[r]);
                    }
                } else {
                    int cc = col - 1024, hh = cc >> 8, d = cc & 255;
                    int bh = (row0 >> 11) * 2 + hh, seq = row0 & 2047;
                    int k = seq & 31;
                    int s = (k >> 4) & 1, hik = (k >> 3) & 1, j0 = k & 7;
                    u32 wrd = pk_fp8<false>(vv[0], vv[1], 0);
                    wrd = pk_fp8<true>(vv[2], vv[3], wrd);
                    u32 boff = (u32)(d * 32 + hik * 16 + s * 8 + j0) ^ (u32)((d & 7) << 4);
                    *reinterpret_cast<u32*>(vd + ((size_t)(bh * 64 + (seq >> 5))) * 8192 + boff) = wrd;
                }
            }
        }
    }
}

// ---------------- gate = sigmoid(sum(rgb_p*event_p, axis=-1)) ----------------
__global__ __launch_bounds__(256) void gate_kernel(const bf16_t* __restrict__ rp,
                                                   const bf16_t* __restrict__ ep,
                                                   float* __restrict__ gate) {
    int row = blockIdx.x * 4 + (threadIdx.x >> 6);
    int lane = threadIdx.x & 63;
    bf16x8 a = reinterpret_cast<const bf16x8*>(rp + (size_t)row * 512)[lane];
    bf16x8 b = reinterpret_cast<const bf16x8*>(ep + (size_t)row * 512)[lane];
    float s = 0.f;
#pragma unroll
    for (int j = 0; j < 8; ++j) s += (float)a[j] * (float)b[j];
#pragma unroll
    for (int off = 32; off; off >>= 1) s += __shfl_xor(s, off, 64);
    if (lane == 0) gate[row] = 1.f / (1.f + __expf(-s));
}

// ---------------- flash attention, FP8, 2-wave blocks ----------------
// grid 1024: bid = qb*32 + dir*16 + bh (32 | 8 -> all qb-blocks of one (dir,bh)
// land on one XCD under default round-robin). 128 threads = 2 waves, wave owns
// 32 q rows (QBLK=64). 4 blocks/CU = 4 independent barrier domains -> one
// block's vmcnt(0)+barrier drain hides under the other three blocks' compute.
// Same R12 inner structure: K epilogue-pre-swizzled, V XOR-swizzled, KVBLK=32.
__global__ __launch_bounds__(128, 4) void attn_kernel(const u8* __restrict__ qbr,
                                                      const u8* __restrict__ qbe,
                                                      const u8* __restrict__ kbr,
                                                      const u8* __restrict__ kbe,
                                                      const u8* __restrict__ vbr,
                                                      const u8* __restrict__ vbe,
                                                      bf16_t* __restrict__ out0,
                                                      bf16_t* __restrict__ out1) {
    __shared__ __align__(16) u8 smem[32768];  // [2 bufs][K 8192 | V 8192]
    const int bid = blockIdx.x;
    const int qb = bid >> 5;                  // 0..31
    const int combo = bid & 31;
    const int dir = combo >> 4;
    const int bh = combo & 15;
    const int b = bh >> 1, h = bh & 1;
    const u8* Qb = dir ? qbe : qbr;
    const u8* Kc = dir ? kbr : kbe;
    const u8* Vc = dir ? vbr : vbe;
    bf16_t* osrc = dir ? out1 : out0;
    const int tid = threadIdx.x;
    const int w = tid >> 6, l = tid & 63;     // w in {0,1}
    const int l31 = l & 31, hi = l >> 5;
    const int q0w = qb * 64 + w * 32;

    // Q fragments: 8 fp8 per dch (elements c = dch*16 + hi*8 + j)
    const u8* qp = Qb + ((size_t)(b * 2048 + q0w + l31)) * 512 + h * 256 + hi * 8;
    uint2 qf[16];
#pragma unroll
    for (int dch = 0; dch < 16; ++dch)
        qf[dch] = *reinterpret_cast<const uint2*>(qp + dch * 16);

    f32x16 O[8] = {};
    float mrun = -1e30f, lrun = 0.f;

    // each wave stages 4KB of K and 4KB of V (4 + 4 gload16 per thread)
    const u8* kq = Kc + (size_t)bh * 524288 + w * 4096 + l * 16;
    const u8* vq = Vc + (size_t)bh * 524288 + w * 4096 + l * 16;

#define STAGE(T, P)                                                          \
    do {                                                                     \
        const u8* ks_ = kq + (size_t)(T) * 8192;                             \
        const u8* vs_ = vq + (size_t)(T) * 8192;                             \
        gload16(ks_, &smem[(P) * 16384 + w * 4096]);                         \
        gload16(ks_ + 1024, &smem[(P) * 16384 + w * 4096 + 1024]);           \
        gload16(ks_ + 2048, &smem[(P) * 16384 + w * 4096 + 2048]);           \
        gload16(ks_ + 3072, &smem[(P) * 16384 + w * 4096 + 3072]);           \
        gload16(vs_, &smem[(P) * 16384 + 8192 + w * 4096]);                  \
        gload16(vs_ + 1024, &smem[(P) * 16384 + 8192 + w * 4096 + 1024]);    \
        gload16(vs_ + 2048, &smem[(P) * 16384 + 8192 + w * 4096 + 2048]);    \
        gload16(vs_ + 3072, &smem[(P) * 16384 + 8192 + w * 4096 + 3072]);    \
    } while (0)

    STAGE(0, 0);

    const u32 kx = (u32)((l31 & 7) << 4);
    for (int kt2 = 0; kt2 < 64; ++kt2) {
        asm volatile("s_waitcnt vmcnt(0)" ::: "memory");
        __builtin_amdgcn_s_barrier();
        if (kt2 < 63) STAGE(kt2 + 1, (kt2 + 1) & 1);

        const int cb = kt2 & 1;
        const u8* kbp = &smem[cb * 16384] + l31 * 256 + hi * 128;
        const u8* vg = &smem[cb * 16384 + 8192] + (((u32)(l31 * 32 + hi * 16)) ^ kx);

        // QK^T (swapped): one b128 feeds two fp8 MFMAs; st[r] k = (r&3)+8(r>>2)+4hi
        f32x16 st = {};
        __builtin_amdgcn_s_setprio(1);
#pragma unroll
        for (int m = 0; m < 8; ++m) {
            uint4 kk = *reinterpret_cast<const uint4*>(kbp + (((u32)(m << 4)) ^ kx));
            st = mfma_fp8(pk64(kk.x, kk.y), pk64(qf[2 * m].x, qf[2 * m].y), st);
            st = mfma_fp8(pk64(kk.z, kk.w), pk64(qf[2 * m + 1].x, qf[2 * m + 1].y), st);
        }
        __builtin_amdgcn_s_setprio(0);

        // scale into exp2 domain: (1/16)*log2(e)
#pragma unroll
        for (int r = 0; r < 16; ++r) st[r] *= 0.090168440f;

        // online softmax (lane-local, q=l31; partner lane ^32 holds other k half)
        float mx = st[0];
#pragma unroll
        for (int r = 1; r < 16; ++r) mx = fmaxf(mx, st[r]);
        mx = fmaxf(mx, __shfl_xor(mx, 32, 64));
        if (__any(mx - mrun > 8.f)) {
            float mnew = fmaxf(mrun, mx);
            float sc = exp2v(mrun - mnew);
            mrun = mnew;
            lrun *= sc;
#pragma unroll
            for (int r = 0; r < 16; ++r) {
                int qr = (r & 3) + 8 * (r >> 2) + 4 * hi;
                float scr = __shfl(sc, qr, 64);
#pragma unroll
                for (int g = 0; g < 8; ++g) O[g][r] *= scr;
            }
        }
        float p_[16];
        float lsum = 0.f;
#pragma unroll
        for (int r = 0; r < 16; ++r) { p_[r] = exp2v(st[r] - mrun); lsum += p_[r]; }
        lsum += __shfl_xor(lsum, 32, 64);
        lrun += lsum;

        // P -> fp8 A-fragments (k = s*16 + hi*8 + j), built via 2 shfl_xor(32)
        u32 X0 = pk_fp8<false>(p_[0], p_[1], 0);   X0 = pk_fp8<true>(p_[2], p_[3], X0);
        u32 X1 = pk_fp8<false>(p_[4], p_[5], 0);   X1 = pk_fp8<true>(p_[6], p_[7], X1);
        u32 X2 = pk_fp8<false>(p_[8], p_[9], 0);   X2 = pk_fp8<true>(p_[10], p_[11], X2);
        u32 X3 = pk_fp8<false>(p_[12], p_[13], 0); X3 = pk_fp8<true>(p_[14], p_[15], X3);
        u32 E0 = (u32)__shfl_xor((int)(hi ? X0 : X1), 32, 64);
        u32 E1 = (u32)__shfl_xor((int)(hi ? X2 : X3), 32, 64);
        long A0 = pk64(hi ? E0 : X0, hi ? X1 : E0);
        long A1 = pk64(hi ? E1 : X2, hi ? X3 : E1);

        // PV: one b128 V read feeds both k-slot MFMAs per 32-d block
        __builtin_amdgcn_s_setprio(1);
#pragma unroll
        for (int g = 0; g < 8; ++g) {
            uint4 v4 = *reinterpret_cast<const uint4*>(vg + g * 1024);
            O[g] = mfma_fp8(A0, pk64(v4.x, v4.y), O[g]);
            O[g] = mfma_fp8(A1, pk64(v4.z, v4.w), O[g]);
        }
        __builtin_amdgcn_s_setprio(0);
    }
#undef STAGE

    // normalize (lrun broadcast per q-row) and store
#pragma unroll
    for (int r = 0; r < 16; ++r) {
        int qr = (r & 3) + 8 * (r >> 2) + 4 * hi;
        float linv = 1.0f / __shfl(lrun, qr, 64);
        size_t rowoff = ((size_t)(b * 2048 + q0w + qr)) * 512 + h * 256 + l31;
#pragma unroll
        for (int g = 0; g < 8; ++g)
            osrc[rowoff + g * 32] = (bf16_t)(O[g][r] * linv);
    }
}

extern "C" void kernel_launch(void* const* d_in, const int* in_sizes, int n_in,
                              void* d_out, int out_size, void* d_ws, size_t ws_size,
                              hipStream_t stream) {
    const float* rgb = (const float*)d_in[0];
    const float* event = (const float*)d_in[1];
    const float* w_rgb = (const float*)d_in[2];
    const float* b_rgb = (const float*)d_in[3];
    const float* w_event = (const float*)d_in[4];
    const float* b_event = (const float*)d_in[5];
    const float* w_in = (const float*)d_in[6];
    const float* b_in = (const float*)d_in[7];
    const float* w_out = (const float*)d_in[8];
    const float* b_out = (const float*)d_in[9];
    float* out = (float*)d_out;

    const size_t MB16 = (size_t)16 * 1024 * 1024;
    char* ws = (char*)d_ws;
    bf16_t* wrgb_bf = (bf16_t*)(ws + 0);
    bf16_t* wevt_bf = (bf16_t*)(ws + 524288);
    bf16_t* wout_bf = (bf16_t*)(ws + 1048576);
    bf16_t* win_bf = (bf16_t*)(ws + 1572864);
    float* gate = (float*)(ws + 3145728);
    bf16_t* bufA = (bf16_t*)(ws + 4194304);            // attn out dir0
    bf16_t* bufB = (bf16_t*)(ws + 4194304 + MB16);     // attn out dir1
    bf16_t* rgbp = (bf16_t*)(ws + 4194304 + 2 * MB16);
    bf16_t* evtp = (bf16_t*)(ws + 4194304 + 3 * MB16);
    u8* qbr = (u8*)(ws + 4194304 + 4 * MB16);
    u8* qbe = (u8*)(ws + 4194304 + 5 * MB16);
    u8* kbr = (u8*)(ws + 4194304 + 6 * MB16);
    u8* kbe = (u8*)(ws + 4194304 + 7 * MB16);
    u8* vbr = (u8*)(ws + 4194304 + 8 * MB16);
    u8* vbe = (u8*)(ws + 4194304 + 9 * MB16);

    dim3 blk(256);
    // weights convert only (inputs are consumed as f32 by the proj GEMM)
    f2b_w<<<768, blk, 0, stream>>>(w_rgb, wrgb_bf, w_event, wevt_bf,
                                   w_in, win_bf, w_out, wout_bf);
    // input projections (merged): y<128 -> rgb, y>=128 -> event; A = f32 direct
    gemm_bt<0><<<dim3(4, 256), blk, 0, stream>>>(rgb, event, nullptr, nullptr,
                                                 wrgb_bf, wevt_bf, b_rgb, b_event,
                                                 rgbp, evtp, nullptr, nullptr, nullptr,
                                                 nullptr, nullptr, nullptr, nullptr, nullptr,
                                                 nullptr, 512, 512);
    // gate
    gate_kernel<<<4096, blk, 0, stream>>>(rgbp, evtp, gate);
    // QKV projections (merged, XCD-swizzled) -> Q/K/V fp8 attention-ready
    gemm_bt<1><<<3072, blk, 0, stream>>>(nullptr, nullptr, rgbp, evtp, win_bf, win_bf,
                                         b_in, b_in, nullptr, nullptr, nullptr, nullptr,
                                         nullptr, qbr, kbr, vbr, qbe, kbe, vbe, 1536, 512);
    // attention both directions (2-wave blocks, 4 barrier domains per CU)
    attn_kernel<<<1024, dim3(128), 0, stream>>>(qbr, qbe, kbr, kbe, vbr, vbe, bufA, bufB);
    // final projection: A-staging = gate-mix(bufA,bufB); f32 out + residual
    gemm_bt<2><<<dim3(4, 128), blk, 0, stream>>>(nullptr, nullptr, bufA, bufB, wout_bf, nullptr,
                                                 b_out, nullptr, out, nullptr, rgbp, evtp, gate,
                                                 nullptr, nullptr, nullptr, nullptr, nullptr,
                                                 nullptr, 512, 512);
}

// Round 15
// 313.244 us; speedup vs baseline: 1.1456x; 1.1456x over previous
//
#include <hip/hip_runtime.h>
#include <hip/hip_bf16.h>
#include <stdint.h>

// B=8, S=2048, D=512, H=2, hd=256. All dims hardcoded.
// 6 dispatches: f2b_w (weights only) -> proj GEMM (A = f32 direct) -> gate
//   -> QKV GEMM (merged, XCD-swizzled; Q/K/V stored FP8 e4m3, K pre-swizzled,
//   V XOR-swizzled) -> attn (FP8 MFMA, KVBLK=32, R12 structure, fma-folded
//   softmax scale) -> final GEMM (mix fused in A-staging, +residual, f32 out)

typedef __bf16 bf16_t;
typedef __bf16 bf16x8 __attribute__((ext_vector_type(8)));
typedef float f32x4 __attribute__((ext_vector_type(4)));
typedef float f32x16 __attribute__((ext_vector_type(16)));
typedef unsigned int u32;
typedef unsigned char u8;

typedef void gvoid_t __attribute__((address_space(1)));
typedef void svoid_t __attribute__((address_space(3)));

__device__ inline void gload16(const void* g, void* l) {
    __builtin_amdgcn_global_load_lds((gvoid_t*)g, (svoid_t*)l, 16, 0, 0);
}

__device__ inline float exp2v(float x) {
    float r;
    asm("v_exp_f32 %0, %1" : "=v"(r) : "v"(x));
    return r;
}

// hiword selector must be a compile-time literal for the builtin.
template <bool HI>
__device__ inline u32 pk_fp8(float a, float b, u32 old) {
    return (u32)__builtin_amdgcn_cvt_pk_fp8_f32(a, b, (int)old, HI);
}
__device__ inline u8 to_fp8(float a) { return (u8)(pk_fp8<false>(a, a, 0) & 0xff); }
__device__ inline long pk64(u32 lo, u32 hi) {
    return (long)(((unsigned long long)hi << 32) | (unsigned long long)lo);
}
__device__ inline f32x16 mfma_fp8(long a, long b, f32x16 c) {
    return __builtin_amdgcn_mfma_f32_32x32x16_fp8_fp8(a, b, c, 0, 0, 0);
}

// ---------------- weights f32 -> bf16 (w_rgb|w_event|w_in|w_out) ------------
__global__ __launch_bounds__(256) void f2b_w(const float* __restrict__ s2, bf16_t* __restrict__ d2,
                                             const float* __restrict__ s3, bf16_t* __restrict__ d3,
                                             const float* __restrict__ s4, bf16_t* __restrict__ d4,
                                             const float* __restrict__ s5, bf16_t* __restrict__ d5) {
    int i = blockIdx.x * 256 + threadIdx.x;
    const float* s; bf16_t* d; int off;
    if (i < 32768)       { s = s2; d = d2; off = i; }
    else if (i < 65536)  { s = s3; d = d3; off = i - 32768; }
    else if (i < 163840) { s = s4; d = d4; off = i - 65536; }
    else                 { s = s5; d = d5; off = i - 163840; }
    const float4* p = reinterpret_cast<const float4*>(s) + (size_t)off * 2;
    float4 a = p[0], b = p[1];
    bf16x8 o;
    o[0] = (bf16_t)a.x; o[1] = (bf16_t)a.y; o[2] = (bf16_t)a.z; o[3] = (bf16_t)a.w;
    o[4] = (bf16_t)b.x; o[5] = (bf16_t)b.y; o[6] = (bf16_t)b.z; o[7] = (bf16_t)b.w;
    reinterpret_cast<bf16x8*>(d)[off] = o;
}

// ---------------- GEMM: C = A @ B^T, 128x128 tile, BK=64, 4 waves ----------
// MODE 0 (proj): A = f32 inputs (reg-staged convert); y<128 rgb else event.
// MODE 1 (QKV, merged, XCD-swizzled grid 3072), all outputs FP8 e4m3:
//   Q -> qdst[row][512] bytes (natural scale)
//   K -> kdst[bh][kt][r*256 + hi_d*128 + (d>>4)*8 + (d&7)] ^ ((r&7)<<4)
//   V -> vdst[bh][kt][(d*32 + hi_k*16 + s*8 + j) ^ ((d&7)<<4)]  (k = s*16+hi_k*8+j)
// MODE 2 (final): A-staging = gate-mix of A,A2; f32 out + residual
template <int MODE>
__global__ __launch_bounds__(256) void gemm_bt(const float* __restrict__ Af,
                                               const float* __restrict__ Af2,
                                               const bf16_t* __restrict__ A,
                                               const bf16_t* __restrict__ A2,
                                               const bf16_t* __restrict__ Bw,
                                               const bf16_t* __restrict__ Bw2,
                                               const float* __restrict__ bias,
                                               const float* __restrict__ bias2,
                                               void* __restrict__ Cout,
                                               void* __restrict__ Cout2,
                                               const bf16_t* __restrict__ r1,
                                               const bf16_t* __restrict__ r2,
                                               const float* __restrict__ gate,
                                               u8* __restrict__ qdst,
                                               u8* __restrict__ kdst,
                                               u8* __restrict__ vdst,
                                               u8* __restrict__ qdst2,
                                               u8* __restrict__ kdst2,
                                               u8* __restrict__ vdst2,
                                               int N, int K) {
    __shared__ __align__(16) bf16_t As[128][64];
    __shared__ __align__(16) bf16_t Bs[128][64];
    const int tid = threadIdx.x, lane = tid & 63, w = tid >> 6;
    const int l16 = lane & 15, l4 = lane >> 4;
    const int wm = w >> 1, wn = w & 1;
    int xt, yt;
    if (MODE == 1) {
        int bid = blockIdx.x;          // 3072 = 12x * 256y, XCD-grouped
        int xcd = bid & 7, idx = bid >> 3;   // idx 0..383
        yt = xcd + 8 * (idx / 12);           // x-fastest within XCD
        xt = idx % 12;
    } else {
        xt = blockIdx.x; yt = blockIdx.y;
    }
    const bool sec = (MODE != 2) && (yt >= 128);
    const size_t a0 = (size_t)(yt & 127) * 128;
    const size_t b0 = (size_t)xt * 128;
    const bf16_t* Ap = sec ? A2 : A;
    const bf16_t* Bp = sec ? Bw2 : Bw;
    const float* Afp = sec ? Af2 : Af;
    const float* bp = sec ? bias2 : bias;
    f32x4 acc[4][4] = {};
    const int srow = w * 32 + (lane >> 3);
    const int scol = (lane & 7) * 8;
    float g4[4];
    if (MODE == 2) {
#pragma unroll
        for (int i = 0; i < 4; ++i) g4[i] = gate[a0 + srow + i * 8];
    }
    for (int kt = 0; kt < K; kt += 64) {
        __syncthreads();
        if (MODE == 0) {
#pragma unroll
            for (int i = 0; i < 4; ++i) {
                const float4* p = reinterpret_cast<const float4*>(
                    Afp + (a0 + srow + i * 8) * (size_t)K + kt + scol);
                float4 x = p[0], y = p[1];
                bf16x8 o;
                o[0] = (bf16_t)x.x; o[1] = (bf16_t)x.y; o[2] = (bf16_t)x.z; o[3] = (bf16_t)x.w;
                o[4] = (bf16_t)y.x; o[5] = (bf16_t)y.y; o[6] = (bf16_t)y.z; o[7] = (bf16_t)y.w;
                *reinterpret_cast<bf16x8*>(&As[srow + i * 8][scol]) = o;
            }
        } else if (MODE == 2) {
#pragma unroll
            for (int i = 0; i < 4; ++i) {
                size_t ro = (a0 + srow + i * 8) * (size_t)K + kt + scol;
                bf16x8 x = *reinterpret_cast<const bf16x8*>(A + ro);
                bf16x8 y = *reinterpret_cast<const bf16x8*>(A2 + ro);
                bf16x8 o;
#pragma unroll
                for (int j = 0; j < 8; ++j)
                    o[j] = (bf16_t)(g4[i] * (float)x[j] + (1.f - g4[i]) * (float)y[j]);
                *reinterpret_cast<bf16x8*>(&As[srow + i * 8][scol]) = o;
            }
        } else {
#pragma unroll
            for (int i = 0; i < 4; ++i)
                gload16(Ap + (a0 + srow + i * 8) * (size_t)K + kt + scol, &As[w * 32 + i * 8][0]);
        }
#pragma unroll
        for (int i = 0; i < 4; ++i)
            gload16(Bp + (b0 + srow + i * 8) * (size_t)K + kt + scol, &Bs[w * 32 + i * 8][0]);
        __syncthreads();
#pragma unroll
        for (int kk = 0; kk < 2; ++kk) {
            bf16x8 af[4], bfr[4];
#pragma unroll
            for (int mi = 0; mi < 4; ++mi)
                af[mi] = *reinterpret_cast<const bf16x8*>(&As[wm * 64 + mi * 16 + l16][kk * 32 + l4 * 8]);
#pragma unroll
            for (int ni = 0; ni < 4; ++ni)
                bfr[ni] = *reinterpret_cast<const bf16x8*>(&Bs[wn * 64 + ni * 16 + l16][kk * 32 + l4 * 8]);
#pragma unroll
            for (int mi = 0; mi < 4; ++mi)
#pragma unroll
                for (int ni = 0; ni < 4; ++ni)
                    acc[mi][ni] = __builtin_amdgcn_mfma_f32_16x16x32_bf16(af[mi], bfr[ni], acc[mi][ni], 0, 0, 0);
        }
    }
    u8* qd = sec ? qdst2 : qdst;
    u8* kd = sec ? kdst2 : kdst;
    u8* vd = sec ? vdst2 : vdst;
#pragma unroll
    for (int mi = 0; mi < 4; ++mi) {
#pragma unroll
        for (int ni = 0; ni < 4; ++ni) {
            int col = (int)b0 + wn * 64 + ni * 16 + l16;
            float bs = bp[col];
            int row0 = (int)a0 + wm * 64 + mi * 16 + l4 * 4;
            float vv[4];
#pragma unroll
            for (int r = 0; r < 4; ++r) vv[r] = acc[mi][ni][r] + bs;
            if (MODE == 0) {
                bf16_t* Cp = (bf16_t*)(sec ? Cout2 : Cout);
#pragma unroll
                for (int r = 0; r < 4; ++r)
                    Cp[(size_t)(row0 + r) * N + col] = (bf16_t)vv[r];
            } else if (MODE == 2) {
#pragma unroll
                for (int r = 0; r < 4; ++r) {
                    size_t idx = (size_t)(row0 + r) * N + col;
                    ((float*)Cout)[idx] = vv[r] + 0.5f * ((float)r1[idx] + (float)r2[idx]);
                }
            } else {
                if (col < 512) {
#pragma unroll
                    for (int r = 0; r < 4; ++r)
                        qd[(size_t)(row0 + r) * 512 + col] = to_fp8(vv[r]);
                } else if (col < 1024) {
                    int cc = col - 512, hh = cc >> 8, d = cc & 255;
                    int dpart = ((d >> 3) & 1) * 128 + (d >> 4) * 8 + (d & 7);
#pragma unroll
                    for (int r = 0; r < 4; ++r) {
                        int row = row0 + r;
                        int bh = (row >> 11) * 2 + hh, seq = row & 2047;
                        int rr = seq & 31;
                        u32 boff = (u32)(rr * 256 + dpart) ^ (u32)((rr & 7) << 4);
                        kd[((size_t)(bh * 64 + (seq >> 5))) * 8192 + boff] = to_fp8(vv[r]);
                    }
                } else {
                    int cc = col - 1024, hh = cc >> 8, d = cc & 255;
                    int bh = (row0 >> 11) * 2 + hh, seq = row0 & 2047;
                    int k = seq & 31;
                    int s = (k >> 4) & 1, hik = (k >> 3) & 1, j0 = k & 7;
                    u32 wrd = pk_fp8<false>(vv[0], vv[1], 0);
                    wrd = pk_fp8<true>(vv[2], vv[3], wrd);
                    u32 boff = (u32)(d * 32 + hik * 16 + s * 8 + j0) ^ (u32)((d & 7) << 4);
                    *reinterpret_cast<u32*>(vd + ((size_t)(bh * 64 + (seq >> 5))) * 8192 + boff) = wrd;
                }
            }
        }
    }
}

// ---------------- gate = sigmoid(sum(rgb_p*event_p, axis=-1)) ----------------
__global__ __launch_bounds__(256) void gate_kernel(const bf16_t* __restrict__ rp,
                                                   const bf16_t* __restrict__ ep,
                                                   float* __restrict__ gate) {
    int row = blockIdx.x * 4 + (threadIdx.x >> 6);
    int lane = threadIdx.x & 63;
    bf16x8 a = reinterpret_cast<const bf16x8*>(rp + (size_t)row * 512)[lane];
    bf16x8 b = reinterpret_cast<const bf16x8*>(ep + (size_t)row * 512)[lane];
    float s = 0.f;
#pragma unroll
    for (int j = 0; j < 8; ++j) s += (float)a[j] * (float)b[j];
#pragma unroll
    for (int off = 32; off; off >>= 1) s += __shfl_xor(s, off, 64);
    if (lane == 0) gate[row] = 1.f / (1.f + __expf(-s));
}

// ---------------- flash attention, FP8, KVBLK=32 (R12 structure) ------------
// grid 512: bid = qb*32 + dir*16 + bh. 4 waves, wave owns 32 q rows.
// K epilogue-pre-swizzled, V XOR-swizzled; one vmcnt(0)+barrier per iter.
// Softmax scale folded via fmaf (mrun/lrun kept in scaled exp2 domain).
__global__ __launch_bounds__(256, 2) void attn_kernel(const u8* __restrict__ qbr,
                                                      const u8* __restrict__ qbe,
                                                      const u8* __restrict__ kbr,
                                                      const u8* __restrict__ kbe,
                                                      const u8* __restrict__ vbr,
                                                      const u8* __restrict__ vbe,
                                                      bf16_t* __restrict__ out0,
                                                      bf16_t* __restrict__ out1) {
    __shared__ __align__(16) u8 smem[32768];  // [2 bufs][K 8192 | V 8192]
    const int bid = blockIdx.x;
    const int qb = bid >> 5;
    const int combo = bid & 31;
    const int dir = combo >> 4;
    const int bh = combo & 15;
    const int b = bh >> 1, h = bh & 1;
    const u8* Qb = dir ? qbe : qbr;
    const u8* Kc = dir ? kbr : kbe;
    const u8* Vc = dir ? vbr : vbe;
    bf16_t* osrc = dir ? out1 : out0;
    const int tid = threadIdx.x;
    const int w = tid >> 6, l = tid & 63;
    const int l31 = l & 31, hi = l >> 5;
    const int q0w = qb * 128 + w * 32;

    // Q fragments: 8 fp8 per dch (elements c = dch*16 + hi*8 + j)
    const u8* qp = Qb + ((size_t)(b * 2048 + q0w + l31)) * 512 + h * 256 + hi * 8;
    uint2 qf[16];
#pragma unroll
    for (int dch = 0; dch < 16; ++dch)
        qf[dch] = *reinterpret_cast<const uint2*>(qp + dch * 16);

    f32x16 O[8] = {};
    float mrun = -1e30f, lrun = 0.f;
    const float SC = 0.090168440f;  // (1/16)*log2(e)

    const u8* kq = Kc + (size_t)bh * 524288 + w * 2048 + l * 16;
    const u8* vq = Vc + (size_t)bh * 524288 + w * 2048 + l * 16;

#define STAGE(T, P)                                                          \
    do {                                                                     \
        const u8* ks_ = kq + (size_t)(T) * 8192;                             \
        const u8* vs_ = vq + (size_t)(T) * 8192;                             \
        gload16(ks_, &smem[(P) * 16384 + w * 2048]);                         \
        gload16(ks_ + 1024, &smem[(P) * 16384 + w * 2048 + 1024]);           \
        gload16(vs_, &smem[(P) * 16384 + 8192 + w * 2048]);                  \
        gload16(vs_ + 1024, &smem[(P) * 16384 + 8192 + w * 2048 + 1024]);    \
    } while (0)

    STAGE(0, 0);

    const u32 kx = (u32)((l31 & 7) << 4);
    for (int kt2 = 0; kt2 < 64; ++kt2) {
        asm volatile("s_waitcnt vmcnt(0)" ::: "memory");
        __builtin_amdgcn_s_barrier();
        if (kt2 < 63) STAGE(kt2 + 1, (kt2 + 1) & 1);

        const int cb = kt2 & 1;
        const u8* kbp = &smem[cb * 16384] + l31 * 256 + hi * 128;
        const u8* vg = &smem[cb * 16384 + 8192] + (((u32)(l31 * 32 + hi * 16)) ^ kx);

        // QK^T (swapped): one b128 feeds two fp8 MFMAs; st[r] k = (r&3)+8(r>>2)+4hi
        f32x16 st = {};
        __builtin_amdgcn_s_setprio(1);
#pragma unroll
        for (int m = 0; m < 8; ++m) {
            uint4 kk = *reinterpret_cast<const uint4*>(kbp + (((u32)(m << 4)) ^ kx));
            st = mfma_fp8(pk64(kk.x, kk.y), pk64(qf[2 * m].x, qf[2 * m].y), st);
            st = mfma_fp8(pk64(kk.z, kk.w), pk64(qf[2 * m + 1].x, qf[2 * m + 1].y), st);
        }
        __builtin_amdgcn_s_setprio(0);

        // online softmax in scaled exp2 domain (scale folded via fmaf)
        float mx = st[0];
#pragma unroll
        for (int r = 1; r < 16; ++r) mx = fmaxf(mx, st[r]);
        mx = fmaxf(mx, __shfl_xor(mx, 32, 64));
        float mxs = mx * SC;
        if (__any(mxs - mrun > 8.f)) {
            float mnew = fmaxf(mrun, mxs);
            float sc = exp2v(mrun - mnew);
            mrun = mnew;
            lrun *= sc;
#pragma unroll
            for (int r = 0; r < 16; ++r) {
                int qr = (r & 3) + 8 * (r >> 2) + 4 * hi;
                float scr = __shfl(sc, qr, 64);
#pragma unroll
                for (int g = 0; g < 8; ++g) O[g][r] *= scr;
            }
        }
        float p_[16];
        float lsum = 0.f;
#pragma unroll
        for (int r = 0; r < 16; ++r) {
            p_[r] = exp2v(fmaf(st[r], SC, -mrun));
            lsum += p_[r];
        }
        lsum += __shfl_xor(lsum, 32, 64);
        lrun += lsum;

        // P -> fp8 A-fragments (k = s*16 + hi*8 + j), built via 2 shfl_xor(32)
        u32 X0 = pk_fp8<false>(p_[0], p_[1], 0);   X0 = pk_fp8<true>(p_[2], p_[3], X0);
        u32 X1 = pk_fp8<false>(p_[4], p_[5], 0);   X1 = pk_fp8<true>(p_[6], p_[7], X1);
        u32 X2 = pk_fp8<false>(p_[8], p_[9], 0);   X2 = pk_fp8<true>(p_[10], p_[11], X2);
        u32 X3 = pk_fp8<false>(p_[12], p_[13], 0); X3 = pk_fp8<true>(p_[14], p_[15], X3);
        u32 E0 = (u32)__shfl_xor((int)(hi ? X0 : X1), 32, 64);
        u32 E1 = (u32)__shfl_xor((int)(hi ? X2 : X3), 32, 64);
        long A0 = pk64(hi ? E0 : X0, hi ? X1 : E0);
        long A1 = pk64(hi ? E1 : X2, hi ? X3 : E1);

        // PV: one b128 V read feeds both k-slot MFMAs per 32-d block
        __builtin_amdgcn_s_setprio(1);
#pragma unroll
        for (int g = 0; g < 8; ++g) {
            uint4 v4 = *reinterpret_cast<const uint4*>(vg + g * 1024);
            O[g] = mfma_fp8(A0, pk64(v4.x, v4.y), O[g]);
            O[g] = mfma_fp8(A1, pk64(v4.z, v4.w), O[g]);
        }
        __builtin_amdgcn_s_setprio(0);
    }
#undef STAGE

    // normalize (lrun broadcast per q-row) and store
#pragma unroll
    for (int r = 0; r < 16; ++r) {
        int qr = (r & 3) + 8 * (r >> 2) + 4 * hi;
        float linv = 1.0f / __shfl(lrun, qr, 64);
        size_t rowoff = ((size_t)(b * 2048 + q0w + qr)) * 512 + h * 256 + l31;
#pragma unroll
        for (int g = 0; g < 8; ++g)
            osrc[rowoff + g * 32] = (bf16_t)(O[g][r] * linv);
    }
}

extern "C" void kernel_launch(void* const* d_in, const int* in_sizes, int n_in,
                              void* d_out, int out_size, void* d_ws, size_t ws_size,
                              hipStream_t stream) {
    const float* rgb = (const float*)d_in[0];
    const float* event = (const float*)d_in[1];
    const float* w_rgb = (const float*)d_in[2];
    const float* b_rgb = (const float*)d_in[3];
    const float* w_event = (const float*)d_in[4];
    const float* b_event = (const float*)d_in[5];
    const float* w_in = (const float*)d_in[6];
    const float* b_in = (const float*)d_in[7];
    const float* w_out = (const float*)d_in[8];
    const float* b_out = (const float*)d_in[9];
    float* out = (float*)d_out;

    const size_t MB16 = (size_t)16 * 1024 * 1024;
    char* ws = (char*)d_ws;
    bf16_t* wrgb_bf = (bf16_t*)(ws + 0);
    bf16_t* wevt_bf = (bf16_t*)(ws + 524288);
    bf16_t* wout_bf = (bf16_t*)(ws + 1048576);
    bf16_t* win_bf = (bf16_t*)(ws + 1572864);
    float* gate = (float*)(ws + 3145728);
    bf16_t* bufA = (bf16_t*)(ws + 4194304);            // attn out dir0
    bf16_t* bufB = (bf16_t*)(ws + 4194304 + MB16);     // attn out dir1
    bf16_t* rgbp = (bf16_t*)(ws + 4194304 + 2 * MB16);
    bf16_t* evtp = (bf16_t*)(ws + 4194304 + 3 * MB16);
    u8* qbr = (u8*)(ws + 4194304 + 4 * MB16);
    u8* qbe = (u8*)(ws + 4194304 + 5 * MB16);
    u8* kbr = (u8*)(ws + 4194304 + 6 * MB16);
    u8* kbe = (u8*)(ws + 4194304 + 7 * MB16);
    u8* vbr = (u8*)(ws + 4194304 + 8 * MB16);
    u8* vbe = (u8*)(ws + 4194304 + 9 * MB16);

    dim3 blk(256);
    // weights convert only (inputs are consumed as f32 by the proj GEMM)
    f2b_w<<<768, blk, 0, stream>>>(w_rgb, wrgb_bf, w_event, wevt_bf,
                                   w_in, win_bf, w_out, wout_bf);
    // input projections (merged): y<128 -> rgb, y>=128 -> event; A = f32 direct
    gemm_bt<0><<<dim3(4, 256), blk, 0, stream>>>(rgb, event, nullptr, nullptr,
                                                 wrgb_bf, wevt_bf, b_rgb, b_event,
                                                 rgbp, evtp, nullptr, nullptr, nullptr,
                                                 nullptr, nullptr, nullptr, nullptr, nullptr,
                                                 nullptr, 512, 512);
    // gate
    gate_kernel<<<4096, blk, 0, stream>>>(rgbp, evtp, gate);
    // QKV projections (merged, XCD-swizzled) -> Q/K/V fp8 attention-ready
    gemm_bt<1><<<3072, blk, 0, stream>>>(nullptr, nullptr, rgbp, evtp, win_bf, win_bf,
                                         b_in, b_in, nullptr, nullptr, nullptr, nullptr,
                                         nullptr, qbr, kbr, vbr, qbe, kbe, vbe, 1536, 512);
    // attention both directions
    attn_kernel<<<512, blk, 0, stream>>>(qbr, qbe, kbr, kbe, vbr, vbe, bufA, bufB);
    // final projection: A-staging = gate-mix(bufA,bufB); f32 out + residual
    gemm_bt<2><<<dim3(4, 128), blk, 0, stream>>>(nullptr, nullptr, bufA, bufB, wout_bf, nullptr,
                                                 b_out, nullptr, out, nullptr, rgbp, evtp, gate,
                                                 nullptr, nullptr, nullptr, nullptr, nullptr,
                                                 nullptr, 512, 512);
}

// Round 16
// 300.761 us; speedup vs baseline: 1.1932x; 1.0415x over previous
//
#include <hip/hip_runtime.h>
#include <hip/hip_bf16.h>
#include <stdint.h>

// B=8, S=2048, D=512, H=2, hd=256. All dims hardcoded.
// 6 dispatches: f2b_w (weights only) -> proj GEMM (A = f32 direct) -> gate
//   -> QKV GEMM (merged, XCD-swizzled; Q/K/V stored FP8 e4m3, K pre-swizzled,
//   V XOR-swizzled) -> attn (FP8 MFMA, KVBLK=32, conflict-free K+V LDS) ->
//   final GEMM (mix fused in A-staging, +residual, f32 out)
// R16 = exact revert to the measured-best R12 configuration (301.1 us).

typedef __bf16 bf16_t;
typedef __bf16 bf16x8 __attribute__((ext_vector_type(8)));
typedef float f32x4 __attribute__((ext_vector_type(4)));
typedef float f32x16 __attribute__((ext_vector_type(16)));
typedef unsigned int u32;
typedef unsigned char u8;

typedef void gvoid_t __attribute__((address_space(1)));
typedef void svoid_t __attribute__((address_space(3)));

__device__ inline void gload16(const void* g, void* l) {
    __builtin_amdgcn_global_load_lds((gvoid_t*)g, (svoid_t*)l, 16, 0, 0);
}

__device__ inline float exp2v(float x) {
    float r;
    asm("v_exp_f32 %0, %1" : "=v"(r) : "v"(x));
    return r;
}

// hiword selector must be a compile-time literal for the builtin.
template <bool HI>
__device__ inline u32 pk_fp8(float a, float b, u32 old) {
    return (u32)__builtin_amdgcn_cvt_pk_fp8_f32(a, b, (int)old, HI);
}
__device__ inline u8 to_fp8(float a) { return (u8)(pk_fp8<false>(a, a, 0) & 0xff); }
__device__ inline long pk64(u32 lo, u32 hi) {
    return (long)(((unsigned long long)hi << 32) | (unsigned long long)lo);
}
__device__ inline f32x16 mfma_fp8(long a, long b, f32x16 c) {
    return __builtin_amdgcn_mfma_f32_32x32x16_fp8_fp8(a, b, c, 0, 0, 0);
}

// ---------------- weights f32 -> bf16 (w_rgb|w_event|w_in|w_out) ------------
__global__ __launch_bounds__(256) void f2b_w(const float* __restrict__ s2, bf16_t* __restrict__ d2,
                                             const float* __restrict__ s3, bf16_t* __restrict__ d3,
                                             const float* __restrict__ s4, bf16_t* __restrict__ d4,
                                             const float* __restrict__ s5, bf16_t* __restrict__ d5) {
    int i = blockIdx.x * 256 + threadIdx.x;
    const float* s; bf16_t* d; int off;
    if (i < 32768)       { s = s2; d = d2; off = i; }
    else if (i < 65536)  { s = s3; d = d3; off = i - 32768; }
    else if (i < 163840) { s = s4; d = d4; off = i - 65536; }
    else                 { s = s5; d = d5; off = i - 163840; }
    const float4* p = reinterpret_cast<const float4*>(s) + (size_t)off * 2;
    float4 a = p[0], b = p[1];
    bf16x8 o;
    o[0] = (bf16_t)a.x; o[1] = (bf16_t)a.y; o[2] = (bf16_t)a.z; o[3] = (bf16_t)a.w;
    o[4] = (bf16_t)b.x; o[5] = (bf16_t)b.y; o[6] = (bf16_t)b.z; o[7] = (bf16_t)b.w;
    reinterpret_cast<bf16x8*>(d)[off] = o;
}

// ---------------- GEMM: C = A @ B^T, 128x128 tile, BK=64, 4 waves ----------
// MODE 0 (proj): A = f32 inputs (reg-staged convert); y<128 rgb else event.
// MODE 1 (QKV, merged, XCD-swizzled grid 3072), all outputs FP8 e4m3:
//   Q -> qdst[row][512] bytes (natural scale)
//   K -> kdst[bh][kt][r*256 + hi_d*128 + (d>>4)*8 + (d&7)] ^ ((r&7)<<4)
//   V -> vdst[bh][kt][(d*32 + hi_k*16 + s*8 + j) ^ ((d&7)<<4)]  (k = s*16+hi_k*8+j)
// MODE 2 (final): A-staging = gate-mix of A,A2; f32 out + residual
template <int MODE>
__global__ __launch_bounds__(256) void gemm_bt(const float* __restrict__ Af,
                                               const float* __restrict__ Af2,
                                               const bf16_t* __restrict__ A,
                                               const bf16_t* __restrict__ A2,
                                               const bf16_t* __restrict__ Bw,
                                               const bf16_t* __restrict__ Bw2,
                                               const float* __restrict__ bias,
                                               const float* __restrict__ bias2,
                                               void* __restrict__ Cout,
                                               void* __restrict__ Cout2,
                                               const bf16_t* __restrict__ r1,
                                               const bf16_t* __restrict__ r2,
                                               const float* __restrict__ gate,
                                               u8* __restrict__ qdst,
                                               u8* __restrict__ kdst,
                                               u8* __restrict__ vdst,
                                               u8* __restrict__ qdst2,
                                               u8* __restrict__ kdst2,
                                               u8* __restrict__ vdst2,
                                               int N, int K) {
    __shared__ __align__(16) bf16_t As[128][64];
    __shared__ __align__(16) bf16_t Bs[128][64];
    const int tid = threadIdx.x, lane = tid & 63, w = tid >> 6;
    const int l16 = lane & 15, l4 = lane >> 4;
    const int wm = w >> 1, wn = w & 1;
    int xt, yt;
    if (MODE == 1) {
        int bid = blockIdx.x;          // 3072 = 12x * 256y, XCD-grouped
        int xcd = bid & 7, idx = bid >> 3;   // idx 0..383
        yt = xcd + 8 * (idx / 12);           // x-fastest within XCD
        xt = idx % 12;
    } else {
        xt = blockIdx.x; yt = blockIdx.y;
    }
    const bool sec = (MODE != 2) && (yt >= 128);
    const size_t a0 = (size_t)(yt & 127) * 128;
    const size_t b0 = (size_t)xt * 128;
    const bf16_t* Ap = sec ? A2 : A;
    const bf16_t* Bp = sec ? Bw2 : Bw;
    const float* Afp = sec ? Af2 : Af;
    const float* bp = sec ? bias2 : bias;
    f32x4 acc[4][4] = {};
    const int srow = w * 32 + (lane >> 3);
    const int scol = (lane & 7) * 8;
    float g4[4];
    if (MODE == 2) {
#pragma unroll
        for (int i = 0; i < 4; ++i) g4[i] = gate[a0 + srow + i * 8];
    }
    for (int kt = 0; kt < K; kt += 64) {
        __syncthreads();
        if (MODE == 0) {
#pragma unroll
            for (int i = 0; i < 4; ++i) {
                const float4* p = reinterpret_cast<const float4*>(
                    Afp + (a0 + srow + i * 8) * (size_t)K + kt + scol);
                float4 x = p[0], y = p[1];
                bf16x8 o;
                o[0] = (bf16_t)x.x; o[1] = (bf16_t)x.y; o[2] = (bf16_t)x.z; o[3] = (bf16_t)x.w;
                o[4] = (bf16_t)y.x; o[5] = (bf16_t)y.y; o[6] = (bf16_t)y.z; o[7] = (bf16_t)y.w;
                *reinterpret_cast<bf16x8*>(&As[srow + i * 8][scol]) = o;
            }
        } else if (MODE == 2) {
#pragma unroll
            for (int i = 0; i < 4; ++i) {
                size_t ro = (a0 + srow + i * 8) * (size_t)K + kt + scol;
                bf16x8 x = *reinterpret_cast<const bf16x8*>(A + ro);
                bf16x8 y = *reinterpret_cast<const bf16x8*>(A2 + ro);
                bf16x8 o;
#pragma unroll
                for (int j = 0; j < 8; ++j)
                    o[j] = (bf16_t)(g4[i] * (float)x[j] + (1.f - g4[i]) * (float)y[j]);
                *reinterpret_cast<bf16x8*>(&As[srow + i * 8][scol]) = o;
            }
        } else {
#pragma unroll
            for (int i = 0; i < 4; ++i)
                gload16(Ap + (a0 + srow + i * 8) * (size_t)K + kt + scol, &As[w * 32 + i * 8][0]);
        }
#pragma unroll
        for (int i = 0; i < 4; ++i)
            gload16(Bp + (b0 + srow + i * 8) * (size_t)K + kt + scol, &Bs[w * 32 + i * 8][0]);
        __syncthreads();
#pragma unroll
        for (int kk = 0; kk < 2; ++kk) {
            bf16x8 af[4], bfr[4];
#pragma unroll
            for (int mi = 0; mi < 4; ++mi)
                af[mi] = *reinterpret_cast<const bf16x8*>(&As[wm * 64 + mi * 16 + l16][kk * 32 + l4 * 8]);
#pragma unroll
            for (int ni = 0; ni < 4; ++ni)
                bfr[ni] = *reinterpret_cast<const bf16x8*>(&Bs[wn * 64 + ni * 16 + l16][kk * 32 + l4 * 8]);
#pragma unroll
            for (int mi = 0; mi < 4; ++mi)
#pragma unroll
                for (int ni = 0; ni < 4; ++ni)
                    acc[mi][ni] = __builtin_amdgcn_mfma_f32_16x16x32_bf16(af[mi], bfr[ni], acc[mi][ni], 0, 0, 0);
        }
    }
    u8* qd = sec ? qdst2 : qdst;
    u8* kd = sec ? kdst2 : kdst;
    u8* vd = sec ? vdst2 : vdst;
#pragma unroll
    for (int mi = 0; mi < 4; ++mi) {
#pragma unroll
        for (int ni = 0; ni < 4; ++ni) {
            int col = (int)b0 + wn * 64 + ni * 16 + l16;
            float bs = bp[col];
            int row0 = (int)a0 + wm * 64 + mi * 16 + l4 * 4;
            float vv[4];
#pragma unroll
            for (int r = 0; r < 4; ++r) vv[r] = acc[mi][ni][r] + bs;
            if (MODE == 0) {
                bf16_t* Cp = (bf16_t*)(sec ? Cout2 : Cout);
#pragma unroll
                for (int r = 0; r < 4; ++r)
                    Cp[(size_t)(row0 + r) * N + col] = (bf16_t)vv[r];
            } else if (MODE == 2) {
#pragma unroll
                for (int r = 0; r < 4; ++r) {
                    size_t idx = (size_t)(row0 + r) * N + col;
                    ((float*)Cout)[idx] = vv[r] + 0.5f * ((float)r1[idx] + (float)r2[idx]);
                }
            } else {
                if (col < 512) {
#pragma unroll
                    for (int r = 0; r < 4; ++r)
                        qd[(size_t)(row0 + r) * 512 + col] = to_fp8(vv[r]);
                } else if (col < 1024) {
                    int cc = col - 512, hh = cc >> 8, d = cc & 255;
                    int dpart = ((d >> 3) & 1) * 128 + (d >> 4) * 8 + (d & 7);
#pragma unroll
                    for (int r = 0; r < 4; ++r) {
                        int row = row0 + r;
                        int bh = (row >> 11) * 2 + hh, seq = row & 2047;
                        int rr = seq & 31;
                        u32 boff = (u32)(rr * 256 + dpart) ^ (u32)((rr & 7) << 4);
                        kd[((size_t)(bh * 64 + (seq >> 5))) * 8192 + boff] = to_fp8(vv[r]);
                    }
                } else {
                    int cc = col - 1024, hh = cc >> 8, d = cc & 255;
                    int bh = (row0 >> 11) * 2 + hh, seq = row0 & 2047;
                    int k = seq & 31;
                    int s = (k >> 4) & 1, hik = (k >> 3) & 1, j0 = k & 7;
                    u32 wrd = pk_fp8<false>(vv[0], vv[1], 0);
                    wrd = pk_fp8<true>(vv[2], vv[3], wrd);
                    u32 boff = (u32)(d * 32 + hik * 16 + s * 8 + j0) ^ (u32)((d & 7) << 4);
                    *reinterpret_cast<u32*>(vd + ((size_t)(bh * 64 + (seq >> 5))) * 8192 + boff) = wrd;
                }
            }
        }
    }
}

// ---------------- gate = sigmoid(sum(rgb_p*event_p, axis=-1)) ----------------
__global__ __launch_bounds__(256) void gate_kernel(const bf16_t* __restrict__ rp,
                                                   const bf16_t* __restrict__ ep,
                                                   float* __restrict__ gate) {
    int row = blockIdx.x * 4 + (threadIdx.x >> 6);
    int lane = threadIdx.x & 63;
    bf16x8 a = reinterpret_cast<const bf16x8*>(rp + (size_t)row * 512)[lane];
    bf16x8 b = reinterpret_cast<const bf16x8*>(ep + (size_t)row * 512)[lane];
    float s = 0.f;
#pragma unroll
    for (int j = 0; j < 8; ++j) s += (float)a[j] * (float)b[j];
#pragma unroll
    for (int off = 32; off; off >>= 1) s += __shfl_xor(s, off, 64);
    if (lane == 0) gate[row] = 1.f / (1.f + __expf(-s));
}

// ---------------- flash attention, FP8, KVBLK=32 (R12 exact) ----------------
// grid 512: bid = qb*32 + dir*16 + bh. 4 waves, wave owns 32 q rows.
// K epilogue-pre-swizzled, V XOR-swizzled; one vmcnt(0)+barrier per iter.
__global__ __launch_bounds__(256, 2) void attn_kernel(const u8* __restrict__ qbr,
                                                      const u8* __restrict__ qbe,
                                                      const u8* __restrict__ kbr,
                                                      const u8* __restrict__ kbe,
                                                      const u8* __restrict__ vbr,
                                                      const u8* __restrict__ vbe,
                                                      bf16_t* __restrict__ out0,
                                                      bf16_t* __restrict__ out1) {
    __shared__ __align__(16) u8 smem[32768];  // [2 bufs][K 8192 | V 8192]
    const int bid = blockIdx.x;
    const int qb = bid >> 5;
    const int combo = bid & 31;
    const int dir = combo >> 4;
    const int bh = combo & 15;
    const int b = bh >> 1, h = bh & 1;
    const u8* Qb = dir ? qbe : qbr;
    const u8* Kc = dir ? kbr : kbe;
    const u8* Vc = dir ? vbr : vbe;
    bf16_t* osrc = dir ? out1 : out0;
    const int tid = threadIdx.x;
    const int w = tid >> 6, l = tid & 63;
    const int l31 = l & 31, hi = l >> 5;
    const int q0w = qb * 128 + w * 32;

    // Q fragments: 8 fp8 per dch (elements c = dch*16 + hi*8 + j)
    const u8* qp = Qb + ((size_t)(b * 2048 + q0w + l31)) * 512 + h * 256 + hi * 8;
    uint2 qf[16];
#pragma unroll
    for (int dch = 0; dch < 16; ++dch)
        qf[dch] = *reinterpret_cast<const uint2*>(qp + dch * 16);

    f32x16 O[8] = {};
    float mrun = -1e30f, lrun = 0.f;

    const u8* kq = Kc + (size_t)bh * 524288 + w * 2048 + l * 16;
    const u8* vq = Vc + (size_t)bh * 524288 + w * 2048 + l * 16;

#define STAGE(T, P)                                                          \
    do {                                                                     \
        const u8* ks_ = kq + (size_t)(T) * 8192;                             \
        const u8* vs_ = vq + (size_t)(T) * 8192;                             \
        gload16(ks_, &smem[(P) * 16384 + w * 2048]);                         \
        gload16(ks_ + 1024, &smem[(P) * 16384 + w * 2048 + 1024]);           \
        gload16(vs_, &smem[(P) * 16384 + 8192 + w * 2048]);                  \
        gload16(vs_ + 1024, &smem[(P) * 16384 + 8192 + w * 2048 + 1024]);    \
    } while (0)

    STAGE(0, 0);

    const u32 kx = (u32)((l31 & 7) << 4);
    for (int kt2 = 0; kt2 < 64; ++kt2) {
        asm volatile("s_waitcnt vmcnt(0)" ::: "memory");
        __builtin_amdgcn_s_barrier();
        if (kt2 < 63) STAGE(kt2 + 1, (kt2 + 1) & 1);

        const int cb = kt2 & 1;
        const u8* kbp = &smem[cb * 16384] + l31 * 256 + hi * 128;
        const u8* vg = &smem[cb * 16384 + 8192] + (((u32)(l31 * 32 + hi * 16)) ^ kx);

        // QK^T (swapped): one b128 feeds two fp8 MFMAs; st[r] k = (r&3)+8(r>>2)+4hi
        f32x16 st = {};
        __builtin_amdgcn_s_setprio(1);
#pragma unroll
        for (int m = 0; m < 8; ++m) {
            uint4 kk = *reinterpret_cast<const uint4*>(kbp + (((u32)(m << 4)) ^ kx));
            st = mfma_fp8(pk64(kk.x, kk.y), pk64(qf[2 * m].x, qf[2 * m].y), st);
            st = mfma_fp8(pk64(kk.z, kk.w), pk64(qf[2 * m + 1].x, qf[2 * m + 1].y), st);
        }
        __builtin_amdgcn_s_setprio(0);

        // scale into exp2 domain: (1/16)*log2(e)
#pragma unroll
        for (int r = 0; r < 16; ++r) st[r] *= 0.090168440f;

        // online softmax (lane-local, q=l31; partner lane ^32 holds other k half)
        float mx = st[0];
#pragma unroll
        for (int r = 1; r < 16; ++r) mx = fmaxf(mx, st[r]);
        mx = fmaxf(mx, __shfl_xor(mx, 32, 64));
        if (__any(mx - mrun > 8.f)) {
            float mnew = fmaxf(mrun, mx);
            float sc = exp2v(mrun - mnew);
            mrun = mnew;
            lrun *= sc;
#pragma unroll
            for (int r = 0; r < 16; ++r) {
                int qr = (r & 3) + 8 * (r >> 2) + 4 * hi;
                float scr = __shfl(sc, qr, 64);
#pragma unroll
                for (int g = 0; g < 8; ++g) O[g][r] *= scr;
            }
        }
        float p_[16];
        float lsum = 0.f;
#pragma unroll
        for (int r = 0; r < 16; ++r) { p_[r] = exp2v(st[r] - mrun); lsum += p_[r]; }
        lsum += __shfl_xor(lsum, 32, 64);
        lrun += lsum;

        // P -> fp8 A-fragments (k = s*16 + hi*8 + j), built via 2 shfl_xor(32)
        u32 X0 = pk_fp8<false>(p_[0], p_[1], 0);   X0 = pk_fp8<true>(p_[2], p_[3], X0);
        u32 X1 = pk_fp8<false>(p_[4], p_[5], 0);   X1 = pk_fp8<true>(p_[6], p_[7], X1);
        u32 X2 = pk_fp8<false>(p_[8], p_[9], 0);   X2 = pk_fp8<true>(p_[10], p_[11], X2);
        u32 X3 = pk_fp8<false>(p_[12], p_[13], 0); X3 = pk_fp8<true>(p_[14], p_[15], X3);
        u32 E0 = (u32)__shfl_xor((int)(hi ? X0 : X1), 32, 64);
        u32 E1 = (u32)__shfl_xor((int)(hi ? X2 : X3), 32, 64);
        long A0 = pk64(hi ? E0 : X0, hi ? X1 : E0);
        long A1 = pk64(hi ? E1 : X2, hi ? X3 : E1);

        // PV: one b128 V read feeds both k-slot MFMAs per 32-d block
        __builtin_amdgcn_s_setprio(1);
#pragma unroll
        for (int g = 0; g < 8; ++g) {
            uint4 v4 = *reinterpret_cast<const uint4*>(vg + g * 1024);
            O[g] = mfma_fp8(A0, pk64(v4.x, v4.y), O[g]);
            O[g] = mfma_fp8(A1, pk64(v4.z, v4.w), O[g]);
        }
        __builtin_amdgcn_s_setprio(0);
    }
#undef STAGE

    // normalize (lrun broadcast per q-row) and store
#pragma unroll
    for (int r = 0; r < 16; ++r) {
        int qr = (r & 3) + 8 * (r >> 2) + 4 * hi;
        float linv = 1.0f / __shfl(lrun, qr, 64);
        size_t rowoff = ((size_t)(b * 2048 + q0w + qr)) * 512 + h * 256 + l31;
#pragma unroll
        for (int g = 0; g < 8; ++g)
            osrc[rowoff + g * 32] = (bf16_t)(O[g][r] * linv);
    }
}

extern "C" void kernel_launch(void* const* d_in, const int* in_sizes, int n_in,
                              void* d_out, int out_size, void* d_ws, size_t ws_size,
                              hipStream_t stream) {
    const float* rgb = (const float*)d_in[0];
    const float* event = (const float*)d_in[1];
    const float* w_rgb = (const float*)d_in[2];
    const float* b_rgb = (const float*)d_in[3];
    const float* w_event = (const float*)d_in[4];
    const float* b_event = (const float*)d_in[5];
    const float* w_in = (const float*)d_in[6];
    const float* b_in = (const float*)d_in[7];
    const float* w_out = (const float*)d_in[8];
    const float* b_out = (const float*)d_in[9];
    float* out = (float*)d_out;

    const size_t MB16 = (size_t)16 * 1024 * 1024;
    char* ws = (char*)d_ws;
    bf16_t* wrgb_bf = (bf16_t*)(ws + 0);
    bf16_t* wevt_bf = (bf16_t*)(ws + 524288);
    bf16_t* wout_bf = (bf16_t*)(ws + 1048576);
    bf16_t* win_bf = (bf16_t*)(ws + 1572864);
    float* gate = (float*)(ws + 3145728);
    bf16_t* bufA = (bf16_t*)(ws + 4194304);            // attn out dir0
    bf16_t* bufB = (bf16_t*)(ws + 4194304 + MB16);     // attn out dir1
    bf16_t* rgbp = (bf16_t*)(ws + 4194304 + 2 * MB16);
    bf16_t* evtp = (bf16_t*)(ws + 4194304 + 3 * MB16);
    u8* qbr = (u8*)(ws + 4194304 + 4 * MB16);
    u8* qbe = (u8*)(ws + 4194304 + 5 * MB16);
    u8* kbr = (u8*)(ws + 4194304 + 6 * MB16);
    u8* kbe = (u8*)(ws + 4194304 + 7 * MB16);
    u8* vbr = (u8*)(ws + 4194304 + 8 * MB16);
    u8* vbe = (u8*)(ws + 4194304 + 9 * MB16);

    dim3 blk(256);
    // weights convert only (inputs are consumed as f32 by the proj GEMM)
    f2b_w<<<768, blk, 0, stream>>>(w_rgb, wrgb_bf, w_event, wevt_bf,
                                   w_in, win_bf, w_out, wout_bf);
    // input projections (merged): y<128 -> rgb, y>=128 -> event; A = f32 direct
    gemm_bt<0><<<dim3(4, 256), blk, 0, stream>>>(rgb, event, nullptr, nullptr,
                                                 wrgb_bf, wevt_bf, b_rgb, b_event,
                                                 rgbp, evtp, nullptr, nullptr, nullptr,
                                                 nullptr, nullptr, nullptr, nullptr, nullptr,
                                                 nullptr, 512, 512);
    // gate
    gate_kernel<<<4096, blk, 0, stream>>>(rgbp, evtp, gate);
    // QKV projections (merged, XCD-swizzled) -> Q/K/V fp8 attention-ready
    gemm_bt<1><<<3072, blk, 0, stream>>>(nullptr, nullptr, rgbp, evtp, win_bf, win_bf,
                                         b_in, b_in, nullptr, nullptr, nullptr, nullptr,
                                         nullptr, qbr, kbr, vbr, qbe, kbe, vbe, 1536, 512);
    // attention both directions
    attn_kernel<<<512, blk, 0, stream>>>(qbr, qbe, kbr, kbe, vbr, vbe, bufA, bufB);
    // final projection: A-staging = gate-mix(bufA,bufB); f32 out + residual
    gemm_bt<2><<<dim3(4, 128), blk, 0, stream>>>(nullptr, nullptr, bufA, bufB, wout_bf, nullptr,
                                                 b_out, nullptr, out, nullptr, rgbp, evtp, gate,
                                                 nullptr, nullptr, nullptr, nullptr, nullptr,
                                                 nullptr, 512, 512);
}